// Round 3
// baseline (132.140 us; speedup 1.0000x reference)
//
#include <hip/hip_runtime.h>

// Problem constants
#define B_  64
#define L_  2048
#define C_  64
#define K_  8
#define F_  24
#define D_  32   // K_ + F_
#define H_  64

// Output layout (flat floats): x_aug [B*L*C] | prob [B*K] | intensity [B*K] | selected_idx [B]
#define XAUG_N   (B_ * L_ * C_)          // 8388608
#define PROB_OFF (XAUG_N)
#define INT_OFF  (PROB_OFF + B_ * K_)
#define SEL_OFF  (INT_OFF + B_ * K_)

#define VEC_PER_BATCH   (L_ * C_ / 4)    // 32768 float4 per batch row
#define BLOCKS_PER_B    16               // 16 blocks per batch
#define VEC_PER_BLOCK   (VEC_PER_BATCH / BLOCKS_PER_B)   // 2048
#define ITERS           (VEC_PER_BLOCK / 256)            // 8 float4 per thread

__device__ __forceinline__ float softplus_f(float v) {
    return fmaxf(v, 0.f) + log1pf(expf(-fabsf(v)));
}

// ---------------------------------------------------------------------------
// Kernel 1: both MLP heads + softmax + softplus + gumbel-softmax + argmax.
// 16 blocks x 256 threads; each block handles 4 batch rows; thread = (row, h).
// Emits per-batch transform descriptor (kind, p0, p1) into ws:
//   kind 0: y = p0*x + p1          (ops 0,1,2,3,5)
//   kind 1: y = p0*tanh(p1*x)      (op 4)
//   kind 2: y = p0*x + p1*sin(x)   (op 6)
//   kind 3: y = p0*x[flip L]       (op 7)
// ---------------------------------------------------------------------------
__global__ void __launch_bounds__(256) head_kernel(
    const float* __restrict__ prev_prob, const float* __restrict__ features,
    const float* __restrict__ gumbel,    const float* __restrict__ log_temp,
    const float* __restrict__ pW1, const float* __restrict__ pb1,
    const float* __restrict__ pW2, const float* __restrict__ pb2,
    const float* __restrict__ pW3, const float* __restrict__ pb3,
    const float* __restrict__ iW1, const float* __restrict__ ib1,
    const float* __restrict__ iW2, const float* __restrict__ ib2,
    const float* __restrict__ iW3, const float* __restrict__ ib3,
    float* __restrict__ out, float* __restrict__ ws)
{
    const int bl = threadIdx.x >> 6;
    const int h  = threadIdx.x & 63;
    const int b  = (blockIdx.x << 2) + bl;

    __shared__ float s_in[4][D_];
    __shared__ float s_a[4][H_];
    __shared__ float s_b[4][H_];
    __shared__ float s_log[4][2 * K_];

    if (h < K_)      s_in[bl][h] = prev_prob[b * K_ + h];
    else if (h < D_) s_in[bl][h] = features[b * F_ + (h - K_)];
    __syncthreads();

    // ---- prob MLP ----
    float acc = pb1[h];
    #pragma unroll
    for (int d = 0; d < D_; ++d) acc = fmaf(s_in[bl][d], pW1[d * H_ + h], acc);
    s_a[bl][h] = fmaxf(acc, 0.f);
    __syncthreads();

    acc = pb2[h];
    #pragma unroll
    for (int d = 0; d < H_; ++d) acc = fmaf(s_a[bl][d], pW2[d * H_ + h], acc);
    s_b[bl][h] = fmaxf(acc, 0.f);
    __syncthreads();

    if (h < K_) {
        acc = pb3[h];
        #pragma unroll
        for (int d = 0; d < H_; ++d) acc = fmaf(s_b[bl][d], pW3[d * K_ + h], acc);
        s_log[bl][h] = acc;
    }
    __syncthreads();

    // ---- intensity MLP ----
    acc = ib1[h];
    #pragma unroll
    for (int d = 0; d < D_; ++d) acc = fmaf(s_in[bl][d], iW1[d * H_ + h], acc);
    s_a[bl][h] = fmaxf(acc, 0.f);
    __syncthreads();

    acc = ib2[h];
    #pragma unroll
    for (int d = 0; d < H_; ++d) acc = fmaf(s_a[bl][d], iW2[d * H_ + h], acc);
    s_b[bl][h] = fmaxf(acc, 0.f);
    __syncthreads();

    if (h < K_) {
        acc = ib3[h];
        #pragma unroll
        for (int d = 0; d < H_; ++d) acc = fmaf(s_b[bl][d], iW3[d * K_ + h], acc);
        s_log[bl][K_ + h] = acc;
    }
    __syncthreads();

    if (h == 0) {
        float plog[K_], ilog[K_];
        #pragma unroll
        for (int k = 0; k < K_; ++k) { plog[k] = s_log[bl][k]; ilog[k] = s_log[bl][K_ + k]; }

        float m = plog[0];
        #pragma unroll
        for (int k = 1; k < K_; ++k) m = fmaxf(m, plog[k]);
        float e[K_], se = 0.f;
        #pragma unroll
        for (int k = 0; k < K_; ++k) { e[k] = expf(plog[k] - m); se += e[k]; }
        #pragma unroll
        for (int k = 0; k < K_; ++k) out[PROB_OFF + b * K_ + k] = e[k] / se;

        float inten[K_];
        #pragma unroll
        for (int k = 0; k < K_; ++k) {
            inten[k] = softplus_f(ilog[k]);
            out[INT_OFF + b * K_ + k] = inten[k];
        }

        float tau = expf(log_temp[0]);
        tau = fminf(fmaxf(tau, 0.01f), 10.0f);
        float z[K_];
        float m2 = -3.4e38f;
        #pragma unroll
        for (int k = 0; k < K_; ++k) {
            z[k] = (plog[k] + gumbel[b * K_ + k]) / tau;
            m2 = fmaxf(m2, z[k]);
        }
        float se2 = 0.f;
        #pragma unroll
        for (int k = 0; k < K_; ++k) { z[k] = expf(z[k] - m2); se2 += z[k]; }
        int idx = 0; float best = z[0];
        #pragma unroll
        for (int k = 1; k < K_; ++k) { if (z[k] > best) { best = z[k]; idx = k; } }

        float ys  = best / se2;
        float sel = (1.0f + ys) - ys;
        out[SEL_OFF + b] = (float)idx;

        const float t = inten[idx];
        int kind; float p0, p1 = 0.f;
        switch (idx) {
            case 0: kind = 0; p0 = sel;                  break;
            case 1: kind = 0; p0 = sel * (1.f + t);      break;
            case 2: kind = 0; p0 = sel; p1 = sel * t;    break;
            case 3: kind = 0; p0 = sel * (1.f - t);      break;
            case 4: kind = 1; p0 = sel; p1 = 1.f + t;    break;
            case 5: kind = 0; p0 = sel * expf(-t);       break;
            case 6: kind = 2; p0 = sel; p1 = sel * t;    break;
            default: kind = 3; p0 = sel;                 break;
        }
        ws[b * 4 + 0] = (float)kind;
        ws[b * 4 + 1] = p0;
        ws[b * 4 + 2] = p1;
    }
}

// ---------------------------------------------------------------------------
// Kernel 2: apply selected transform. 1024 blocks (16/batch), 256 threads,
// 8 float4 per thread issued as independent back-to-back loads for ILP.
// ---------------------------------------------------------------------------
__global__ void __launch_bounds__(256) apply_kernel(
    const float* __restrict__ x, const float* __restrict__ ws,
    float* __restrict__ out)
{
    const int b    = blockIdx.x >> 4;                       // batch row
    const int blk  = blockIdx.x & (BLOCKS_PER_B - 1);
    const int base = blk * VEC_PER_BLOCK + threadIdx.x;     // first float4 idx

    const float4* xb = (const float4*)x + (size_t)b * VEC_PER_BATCH;
    float4*       ob = (float4*)out + (size_t)b * VEC_PER_BATCH;

    const float kf = ws[b * 4 + 0];
    int kind = (int)kf;
    kind = kind < 0 ? 0 : (kind > 3 ? 3 : kind);            // defensive clamp
    const float p0 = ws[b * 4 + 1];
    const float p1 = ws[b * 4 + 2];

    float4 xv[ITERS];
    if (kind == 3) {
        // time reversal: out float4 v -> in float4 at (L-1-l)*16 + c, C/4=16
        #pragma unroll
        for (int i = 0; i < ITERS; ++i) {
            const int v = base + i * 256;
            const int l = v >> 4, c = v & 15;
            xv[i] = xb[(L_ - 1 - l) * 16 + c];
        }
    } else {
        #pragma unroll
        for (int i = 0; i < ITERS; ++i) xv[i] = xb[base + i * 256];
    }

    if (kind == 0) {
        #pragma unroll
        for (int i = 0; i < ITERS; ++i) {
            float4 r;
            r.x = fmaf(p0, xv[i].x, p1);
            r.y = fmaf(p0, xv[i].y, p1);
            r.z = fmaf(p0, xv[i].z, p1);
            r.w = fmaf(p0, xv[i].w, p1);
            ob[base + i * 256] = r;
        }
    } else if (kind == 1) {
        #pragma unroll
        for (int i = 0; i < ITERS; ++i) {
            float4 r;
            r.x = p0 * tanhf(p1 * xv[i].x);
            r.y = p0 * tanhf(p1 * xv[i].y);
            r.z = p0 * tanhf(p1 * xv[i].z);
            r.w = p0 * tanhf(p1 * xv[i].w);
            ob[base + i * 256] = r;
        }
    } else if (kind == 2) {
        #pragma unroll
        for (int i = 0; i < ITERS; ++i) {
            float4 r;
            r.x = fmaf(p0, xv[i].x, p1 * sinf(xv[i].x));
            r.y = fmaf(p0, xv[i].y, p1 * sinf(xv[i].y));
            r.z = fmaf(p0, xv[i].z, p1 * sinf(xv[i].z));
            r.w = fmaf(p0, xv[i].w, p1 * sinf(xv[i].w));
            ob[base + i * 256] = r;
        }
    } else {
        #pragma unroll
        for (int i = 0; i < ITERS; ++i) {
            float4 r;
            r.x = p0 * xv[i].x; r.y = p0 * xv[i].y;
            r.z = p0 * xv[i].z; r.w = p0 * xv[i].w;
            ob[base + i * 256] = r;
        }
    }
}

extern "C" void kernel_launch(void* const* d_in, const int* in_sizes, int n_in,
                              void* d_out, int out_size, void* d_ws, size_t ws_size,
                              hipStream_t stream) {
    const float* x         = (const float*)d_in[0];
    const float* prev_prob = (const float*)d_in[1];
    const float* features  = (const float*)d_in[2];
    const float* gumbel    = (const float*)d_in[3];
    const float* log_temp  = (const float*)d_in[4];
    const float* pW1 = (const float*)d_in[5];
    const float* pb1 = (const float*)d_in[6];
    const float* pW2 = (const float*)d_in[7];
    const float* pb2 = (const float*)d_in[8];
    const float* pW3 = (const float*)d_in[9];
    const float* pb3 = (const float*)d_in[10];
    const float* iW1 = (const float*)d_in[11];
    const float* ib1 = (const float*)d_in[12];
    const float* iW2 = (const float*)d_in[13];
    const float* ib2 = (const float*)d_in[14];
    const float* iW3 = (const float*)d_in[15];
    const float* ib3 = (const float*)d_in[16];

    float* out = (float*)d_out;
    float* ws  = (float*)d_ws;

    hipLaunchKernelGGL(head_kernel, dim3(B_ / 4), dim3(256), 0, stream,
                       prev_prob, features, gumbel, log_temp,
                       pW1, pb1, pW2, pb2, pW3, pb3,
                       iW1, ib1, iW2, ib2, iW3, ib3,
                       out, ws);

    hipLaunchKernelGGL(apply_kernel, dim3(B_ * BLOCKS_PER_B), dim3(256), 0, stream,
                       x, ws, out);
}

// Round 5
// 122.792 us; speedup vs baseline: 1.0761x; 1.0761x over previous
//
#include <hip/hip_runtime.h>

// Problem constants
#define B_  64
#define L_  2048
#define C_  64
#define K_  8
#define F_  24
#define D_  32   // K_ + F_
#define H_  64

// Output layout (flat floats): x_aug [B*L*C] | prob [B*K] | intensity [B*K] | selected_idx [B]
#define XAUG_N   (B_ * L_ * C_)          // 8388608
#define PROB_OFF (XAUG_N)
#define INT_OFF  (PROB_OFF + B_ * K_)
#define SEL_OFF  (INT_OFF + B_ * K_)

#define VEC_PER_BATCH   (L_ * C_ / 4)    // 32768 float4 per batch row
#define BLOCKS_PER_B    16               // 16 blocks per batch
#define VEC_PER_BLOCK   (VEC_PER_BATCH / BLOCKS_PER_B)   // 2048
#define ITERS           (VEC_PER_BLOCK / 256)            // 8 float4 per thread

__device__ __forceinline__ float softplus_f(float v) {
    return fmaxf(v, 0.f) + log1pf(expf(-fabsf(v)));
}

// ---------------------------------------------------------------------------
// Single fused kernel. 1024 blocks (16 per batch row) x 256 threads.
// Wave 0 of every block redundantly computes the head (two 32->64->64->8 MLPs
// + softmax/softplus/gumbel/argmax) for its OWN batch row -> descriptor in
// LDS. Weights are 54 KB total, L2-resident across all blocks, so the
// redundancy costs no HBM traffic. Then all 256 threads stream 8 float4 each
// of the selected transform:
//   kind 0: y = p0*x + p1          (ops 0,1,2,3,5)
//   kind 1: y = p0*tanh(p1*x)      (op 4)
//   kind 2: y = p0*x + p1*sin(x)   (op 6)
//   kind 3: y = p0*x[flip L]       (op 7)
// The blk==0 block of each batch also writes prob/intensity/selected_idx.
// No inter-block dependency of any kind (G16-safe).
// ---------------------------------------------------------------------------
__global__ void __launch_bounds__(256) fused_kernel(
    const float* __restrict__ x,
    const float* __restrict__ prev_prob, const float* __restrict__ features,
    const float* __restrict__ gumbel,    const float* __restrict__ log_temp,
    const float* __restrict__ pW1, const float* __restrict__ pb1,
    const float* __restrict__ pW2, const float* __restrict__ pb2,
    const float* __restrict__ pW3, const float* __restrict__ pb3,
    const float* __restrict__ iW1, const float* __restrict__ ib1,
    const float* __restrict__ iW2, const float* __restrict__ ib2,
    const float* __restrict__ iW3, const float* __restrict__ ib3,
    float* __restrict__ out)
{
    const int b   = blockIdx.x >> 4;                 // batch row
    const int blk = blockIdx.x & (BLOCKS_PER_B - 1); // slab within batch
    const int tid = threadIdx.x;

    __shared__ float s_in[D_];
    __shared__ float s_a[H_];
    __shared__ float s_b[H_];
    __shared__ float s_log[2 * K_];
    __shared__ float s_desc[4];   // kind, p0, p1

    const int h = tid;  // hidden unit when tid < 64

    if (tid < D_) s_in[tid] = (tid < K_) ? prev_prob[b * K_ + tid]
                                         : features[b * F_ + (tid - K_)];
    __syncthreads();

    if (tid < H_) {
        float acc = pb1[h];
        #pragma unroll
        for (int d = 0; d < D_; ++d) acc = fmaf(s_in[d], pW1[d * H_ + h], acc);
        s_a[h] = fmaxf(acc, 0.f);
    }
    __syncthreads();

    if (tid < H_) {
        float acc = pb2[h];
        #pragma unroll
        for (int d = 0; d < H_; ++d) acc = fmaf(s_a[d], pW2[d * H_ + h], acc);
        s_b[h] = fmaxf(acc, 0.f);
    }
    __syncthreads();

    if (tid < K_) {
        float acc = pb3[h];
        #pragma unroll
        for (int d = 0; d < H_; ++d) acc = fmaf(s_b[d], pW3[d * K_ + h], acc);
        s_log[h] = acc;
    }
    __syncthreads();

    if (tid < H_) {
        float acc = ib1[h];
        #pragma unroll
        for (int d = 0; d < D_; ++d) acc = fmaf(s_in[d], iW1[d * H_ + h], acc);
        s_a[h] = fmaxf(acc, 0.f);
    }
    __syncthreads();

    if (tid < H_) {
        float acc = ib2[h];
        #pragma unroll
        for (int d = 0; d < H_; ++d) acc = fmaf(s_a[d], iW2[d * H_ + h], acc);
        s_b[h] = fmaxf(acc, 0.f);
    }
    __syncthreads();

    if (tid < K_) {
        float acc = ib3[h];
        #pragma unroll
        for (int d = 0; d < H_; ++d) acc = fmaf(s_b[d], iW3[d * K_ + h], acc);
        s_log[K_ + h] = acc;
    }
    __syncthreads();

    if (tid == 0) {
        float plog[K_], ilog[K_];
        #pragma unroll
        for (int k = 0; k < K_; ++k) { plog[k] = s_log[k]; ilog[k] = s_log[K_ + k]; }

        float m = plog[0];
        #pragma unroll
        for (int k = 1; k < K_; ++k) m = fmaxf(m, plog[k]);
        float e[K_], se = 0.f;
        #pragma unroll
        for (int k = 0; k < K_; ++k) { e[k] = expf(plog[k] - m); se += e[k]; }

        float inten[K_];
        #pragma unroll
        for (int k = 0; k < K_; ++k) inten[k] = softplus_f(ilog[k]);

        float tau = expf(log_temp[0]);
        tau = fminf(fmaxf(tau, 0.01f), 10.0f);
        float z[K_], m2 = -3.4e38f;
        #pragma unroll
        for (int k = 0; k < K_; ++k) {
            z[k] = (plog[k] + gumbel[b * K_ + k]) / tau;
            m2 = fmaxf(m2, z[k]);
        }
        float se2 = 0.f;
        #pragma unroll
        for (int k = 0; k < K_; ++k) { z[k] = expf(z[k] - m2); se2 += z[k]; }
        int idx = 0; float best = z[0];
        #pragma unroll
        for (int k = 1; k < K_; ++k) { if (z[k] > best) { best = z[k]; idx = k; } }

        float ys  = best / se2;
        float sel = (1.0f + ys) - ys;   // straight-through value

        if (blk == 0) {
            #pragma unroll
            for (int k = 0; k < K_; ++k) out[PROB_OFF + b * K_ + k] = e[k] / se;
            #pragma unroll
            for (int k = 0; k < K_; ++k) out[INT_OFF + b * K_ + k] = inten[k];
            out[SEL_OFF + b] = (float)idx;
        }

        const float t = inten[idx];
        int kind; float p0, p1 = 0.f;
        switch (idx) {
            case 0: kind = 0; p0 = sel;                  break;
            case 1: kind = 0; p0 = sel * (1.f + t);      break;
            case 2: kind = 0; p0 = sel; p1 = sel * t;    break;
            case 3: kind = 0; p0 = sel * (1.f - t);      break;
            case 4: kind = 1; p0 = sel; p1 = 1.f + t;    break;
            case 5: kind = 0; p0 = sel * expf(-t);       break;
            case 6: kind = 2; p0 = sel; p1 = sel * t;    break;
            default: kind = 3; p0 = sel;                 break;
        }
        s_desc[0] = (float)kind; s_desc[1] = p0; s_desc[2] = p1;
    }
    __syncthreads();

    // ---- apply: all 256 threads, 8 float4 each ----
    int kind = (int)s_desc[0];
    kind = kind < 0 ? 0 : (kind > 3 ? 3 : kind);   // defensive clamp
    const float p0 = s_desc[1];
    const float p1 = s_desc[2];

    const int base = blk * VEC_PER_BLOCK + tid;
    const float4* xb = (const float4*)x + (size_t)b * VEC_PER_BATCH;
    float4*       ob = (float4*)out + (size_t)b * VEC_PER_BATCH;

    float4 xv[ITERS];
    if (kind == 3) {
        // time reversal: out float4 v -> in float4 at (L-1-l)*16 + c  (C/4=16)
        #pragma unroll
        for (int i = 0; i < ITERS; ++i) {
            const int v = base + i * 256;
            const int l = v >> 4, c = v & 15;
            xv[i] = xb[(L_ - 1 - l) * 16 + c];
        }
    } else {
        #pragma unroll
        for (int i = 0; i < ITERS; ++i) xv[i] = xb[base + i * 256];
    }

    if (kind == 0) {
        #pragma unroll
        for (int i = 0; i < ITERS; ++i) {
            float4 r;
            r.x = fmaf(p0, xv[i].x, p1);
            r.y = fmaf(p0, xv[i].y, p1);
            r.z = fmaf(p0, xv[i].z, p1);
            r.w = fmaf(p0, xv[i].w, p1);
            ob[base + i * 256] = r;
        }
    } else if (kind == 1) {
        #pragma unroll
        for (int i = 0; i < ITERS; ++i) {
            float4 r;
            r.x = p0 * tanhf(p1 * xv[i].x);
            r.y = p0 * tanhf(p1 * xv[i].y);
            r.z = p0 * tanhf(p1 * xv[i].z);
            r.w = p0 * tanhf(p1 * xv[i].w);
            ob[base + i * 256] = r;
        }
    } else if (kind == 2) {
        #pragma unroll
        for (int i = 0; i < ITERS; ++i) {
            float4 r;
            r.x = fmaf(p0, xv[i].x, p1 * sinf(xv[i].x));
            r.y = fmaf(p0, xv[i].y, p1 * sinf(xv[i].y));
            r.z = fmaf(p0, xv[i].z, p1 * sinf(xv[i].z));
            r.w = fmaf(p0, xv[i].w, p1 * sinf(xv[i].w));
            ob[base + i * 256] = r;
        }
    } else {
        #pragma unroll
        for (int i = 0; i < ITERS; ++i) {
            float4 r;
            r.x = p0 * xv[i].x; r.y = p0 * xv[i].y;
            r.z = p0 * xv[i].z; r.w = p0 * xv[i].w;
            ob[base + i * 256] = r;
        }
    }
}

extern "C" void kernel_launch(void* const* d_in, const int* in_sizes, int n_in,
                              void* d_out, int out_size, void* d_ws, size_t ws_size,
                              hipStream_t stream) {
    const float* x         = (const float*)d_in[0];
    const float* prev_prob = (const float*)d_in[1];
    const float* features  = (const float*)d_in[2];
    const float* gumbel    = (const float*)d_in[3];
    const float* log_temp  = (const float*)d_in[4];
    const float* pW1 = (const float*)d_in[5];
    const float* pb1 = (const float*)d_in[6];
    const float* pW2 = (const float*)d_in[7];
    const float* pb2 = (const float*)d_in[8];
    const float* pW3 = (const float*)d_in[9];
    const float* pb3 = (const float*)d_in[10];
    const float* iW1 = (const float*)d_in[11];
    const float* ib1 = (const float*)d_in[12];
    const float* iW2 = (const float*)d_in[13];
    const float* ib2 = (const float*)d_in[14];
    const float* iW3 = (const float*)d_in[15];
    const float* ib3 = (const float*)d_in[16];

    float* out = (float*)d_out;

    hipLaunchKernelGGL(fused_kernel, dim3(B_ * BLOCKS_PER_B), dim3(256), 0, stream,
                       x, prev_prob, features, gumbel, log_temp,
                       pW1, pb1, pW2, pb2, pW3, pb3,
                       iW1, ib1, iW2, ib2, iW3, ib3,
                       out);
}